// Round 9
// baseline (840.499 us; speedup 1.0000x reference)
//
#include <hip/hip_runtime.h>
#include <hip/hip_fp16.h>
#include <cstdint>
#include <cstddef>

constexpr int NN  = 100000;
constexpr int EE  = 1600000;
constexpr int HID = 128;
constexpr int BUK = 256;                      // nodes per bucket (local id fits 8 bits)
constexpr int NBUK = (NN + BUK - 1) / BUK;    // 391 buckets
constexpr int BLKE = 2048;                    // edges per block in bucket passes
constexpr int NBE  = (EE + BLKE - 1) / BLKE;  // 782 edge blocks
constexpr int MH   = NBUK * NBE;              // 305762 flattened hist entries
constexpr int MH2  = 2 * MH;                  // concatenated dst|src histograms
constexpr int NSC  = (MH2 + 2047) / 2048;     // 299 scan chunks (<=512 for scan_top)

typedef float f32x4_t __attribute__((ext_vector_type(4)));
typedef short bf16x8_t __attribute__((ext_vector_type(8)));

static __device__ __forceinline__ short f2bf(float f) {
    union { float f; unsigned u; } x; x.f = f;
    unsigned r = x.u + 0x7FFF + ((x.u >> 16) & 1);   // RN-even
    return (short)(r >> 16);
}
static __device__ __forceinline__ float bf2f(short b) {
    union { unsigned u; float f; } x; x.u = ((unsigned)(unsigned short)b) << 16;
    return x.f;
}

// ---------------------------------------------------------------- pass 1: per-block bucket histograms, both sides (LDS atomics only)
// dst half -> bh2[0..MH), src half -> bh2[MH..2MH)
__global__ __launch_bounds__(256) void bh_both_k(const int* __restrict__ src, const int* __restrict__ dst,
                                                 int* __restrict__ bh2) {
    __shared__ int hd[NBUK], hs[NBUK];
    int blk = blockIdx.x, t = threadIdx.x;
    for (int i = t; i < NBUK; i += 256) { hd[i] = 0; hs[i] = 0; }
    __syncthreads();
    int e0 = blk * BLKE, e1 = min(e0 + BLKE, EE);
    for (int e = e0 + t; e < e1; e += 256) {
        atomicAdd(&hd[dst[e] >> 8], 1);
        atomicAdd(&hs[src[e] >> 8], 1);
    }
    __syncthreads();
    for (int i = t; i < NBUK; i += 256) {
        bh2[i * NBE + blk]      = hd[i];
        bh2[MH + i * NBE + blk] = hs[i];
    }
}

// ---------------------------------------------------------------- 3-level exclusive scan over 2*MH (2048 elems/block)
__global__ __launch_bounds__(256) void scan_sum_k(const int* __restrict__ in, int* __restrict__ bsum, int n) {
    __shared__ int sc[256];
    int b = blockIdx.x, t = threadIdx.x;
    int base = b * 2048 + t * 8;
    int s = 0;
#pragma unroll
    for (int j = 0; j < 8; j++) { int idx = base + j; s += (idx < n) ? in[idx] : 0; }
    sc[t] = s; __syncthreads();
    for (int off = 128; off > 0; off >>= 1) {
        if (t < off) sc[t] += sc[t + off];
        __syncthreads();
    }
    if (t == 0) bsum[b] = sc[0];
}

__global__ __launch_bounds__(512) void scan_top_k(const int* __restrict__ bsum, int* __restrict__ boff, int nb) {
    __shared__ int sc[512];
    int t = threadIdx.x;
    int v = (t < nb) ? bsum[t] : 0;
    sc[t] = v; __syncthreads();
    for (int off = 1; off < 512; off <<= 1) {
        int u = (t >= off) ? sc[t - off] : 0;
        __syncthreads();
        sc[t] += u;
        __syncthreads();
    }
    if (t < nb) boff[t] = sc[t] - v;
}

__global__ __launch_bounds__(256) void scan_chunk_k(const int* __restrict__ in, const int* __restrict__ boff,
                                                    int* __restrict__ out, int n) {
    __shared__ int sc[256];
    int b = blockIdx.x, t = threadIdx.x;
    int base = b * 2048 + t * 8;
    int c[8];
    int s = 0;
#pragma unroll
    for (int j = 0; j < 8; j++) { int idx = base + j; c[j] = (idx < n) ? in[idx] : 0; s += c[j]; }
    sc[t] = s; __syncthreads();
    for (int off = 1; off < 256; off <<= 1) {
        int v = (t >= off) ? sc[t - off] : 0;
        __syncthreads();
        sc[t] += v;
        __syncthreads();
    }
    int excl = sc[t] - s + boff[b];
#pragma unroll
    for (int j = 0; j < 8; j++) {
        int idx = base + j;
        if (idx < n) out[idx] = excl;
        excl += c[j];
    }
}

// ---------------------------------------------------------------- pass 2: scatter into bucket order (LDS cursors)
// dst side: packed 25-bit payload (d_local<<17 | src); src side: low byte only
// src-half offsets carry +EE (concatenated scan) -> subtract at cursor load
__global__ __launch_bounds__(256) void scatter_both_k(const int* __restrict__ src, const int* __restrict__ dst,
                                                      const int* __restrict__ off2,
                                                      unsigned* __restrict__ pairs, unsigned char* __restrict__ sbyte) {
    __shared__ int cd[NBUK], cs[NBUK];
    int blk = blockIdx.x, t = threadIdx.x;
    for (int i = t; i < NBUK; i += 256) {
        cd[i] = off2[i * NBE + blk];
        cs[i] = off2[MH + i * NBE + blk] - EE;
    }
    __syncthreads();
    int e0 = blk * BLKE, e1 = min(e0 + BLKE, EE);
    for (int e = e0 + t; e < e1; e += 256) {
        int d = dst[e], s = src[e];
        int pd = atomicAdd(&cd[d >> 8], 1);
        pairs[pd] = ((unsigned)(d & 255) << 17) | (unsigned)s;
        int ps = atomicAdd(&cs[s >> 8], 1);
        sbyte[ps] = (unsigned char)(s & 255);
    }
}

// ---------------------------------------------------------------- per-bucket work, fused:
// blocks [0, NBUK):     in-deg hist -> inorm, rowptr, col  (from pairs)
// blocks [NBUK, 2*NBUK): out-deg hist -> onorm             (from sbyte)
__global__ __launch_bounds__(512) void bucket_csr_ocnt_k(
    const unsigned* __restrict__ pairs, const unsigned char* __restrict__ sbyte,
    const int* __restrict__ off2,
    int* __restrict__ rowptr, int* __restrict__ col,
    float* __restrict__ inorm, float* __restrict__ onorm) {
    __shared__ int hist[BUK];
    __shared__ int excl[BUK];
    __shared__ int psum[BUK];
    int t = threadIdx.x;

    if (blockIdx.x >= NBUK) {            // -------- out-degree counting
        int b = blockIdx.x - NBUK;
        int base = off2[MH + b * NBE] - EE;
        int endv = (b == NBUK - 1) ? EE : off2[MH + (b + 1) * NBE] - EE;
        if (t < BUK) hist[t] = 0;
        __syncthreads();
        for (int i = base + t; i < endv; i += 512) atomicAdd(&hist[sbyte[i]], 1);
        __syncthreads();
        if (t < BUK) {
            int node = b * BUK + t;
            if (node < NN) {
                int c = hist[t]; if (c < 1) c = 1;
                onorm[node] = rsqrtf((float)c);
            }
        }
        return;
    }

    // ------------------------------------------- CSR build
    int b = blockIdx.x;
    int base = off2[b * NBE];
    int endv = (b == NBUK - 1) ? EE : off2[(b + 1) * NBE];
    if (t < BUK) hist[t] = 0;
    __syncthreads();
    for (int i = base + t; i < endv; i += 512) atomicAdd(&hist[pairs[i] >> 17], 1);
    __syncthreads();
    int ps = 0;
    if (t < BUK) { ps = hist[t]; psum[t] = ps; }
    __syncthreads();
    for (int off = 1; off < BUK; off <<= 1) {
        int u = 0;
        if (t < BUK && t >= off) u = psum[t - off];
        __syncthreads();
        if (t < BUK) psum[t] += u;
        __syncthreads();
    }
    if (t < BUK) {
        int pex = psum[t] - ps;
        excl[t] = pex;
        int node = b * BUK + t;
        if (node < NN) {
            rowptr[node] = base + pex;
            int c = ps; if (c < 1) c = 1;
            inorm[node] = rsqrtf((float)c);
        }
    }
    if (b == NBUK - 1 && t == 0) rowptr[NN] = EE;
    __syncthreads();
    for (int i = base + t; i < endv; i += 512) {
        unsigned p = pairs[i];
        int pos = base + atomicAdd(&excl[p >> 17], 1);
        col[pos] = (int)(p & 0x1FFFFu);
    }
}

// ---------------------------------------------------------------- W12 = W1 @ W2 ; b12 = b1 @ W2 + b2 (merged)
__global__ __launch_bounds__(256) void w12_k(const float* __restrict__ W1, const float* __restrict__ W2,
                                             const float* __restrict__ b1, const float* __restrict__ b2,
                                             float* __restrict__ W12, float* __restrict__ b12) {
    if (blockIdx.x == 64) {
        int j = threadIdx.x;
        if (j < 128) {
            float acc = b2[j];
            for (int k = 0; k < 128; k++) acc = fmaf(b1[k], W2[k * 128 + j], acc);
            b12[j] = acc;
        }
        return;
    }
    int idx = blockIdx.x * 256 + threadIdx.x;   // 0..16383
    int i = idx >> 7, j = idx & 127;
    float a0 = 0.f, a1 = 0.f, a2 = 0.f, a3 = 0.f;
    for (int k = 0; k < 128; k += 4) {
        a0 = fmaf(W1[i * 128 + k],     W2[(k)     * 128 + j], a0);
        a1 = fmaf(W1[i * 128 + k + 1], W2[(k + 1) * 128 + j], a1);
        a2 = fmaf(W1[i * 128 + k + 2], W2[(k + 2) * 128 + j], a2);
        a3 = fmaf(W1[i * 128 + k + 3], W2[(k + 3) * 128 + j], a3);
    }
    W12[idx] = (a0 + a1) + (a2 + a3);
}

// ---------------------------------------------------------------- aggregation (fp16 gather, fp32 acc, split-bf16 out)
// R0-proven gather: one wave per dst node; quarter-wave (16 lanes x 16B =
// one 256B fp16 row), 4 edges in flight per quarter, 1-edge tail. h16 is
// pre-scaled by onorm. R8: epilogue scales by inorm and emits SPLIT-BF16
// planes (hi, lo) directly (bit-identical to the GEMM's old conversion).
__global__ __launch_bounds__(256) void agg_k(const float4* __restrict__ h16, const int* __restrict__ rowptr,
                                             const int* __restrict__ col, const float* __restrict__ inorm,
                                             short* __restrict__ h0h, short* __restrict__ h0l) {
    int w = (int)((blockIdx.x * 256 + threadIdx.x) >> 6);
    if (w >= NN) return;
    int lane = threadIdx.x & 63;
    int q   = lane >> 4;
    int l16 = lane & 15;
    int beg = rowptr[w], end = rowptr[w + 1];
    float acc[8];
#pragma unroll
    for (int j = 0; j < 8; j++) acc[j] = 0.f;

    union HU { float4 f4; __half2 h2[4]; };
    int i = beg + q;
    for (; i + 12 < end; i += 16) {        // per quarter: edges i, i+4, i+8, i+12
        int s0 = col[i], s1 = col[i + 4], s2 = col[i + 8], s3 = col[i + 12];
        HU u0, u1, u2, u3;
        u0.f4 = h16[(size_t)s0 * 16 + l16];
        u1.f4 = h16[(size_t)s1 * 16 + l16];
        u2.f4 = h16[(size_t)s2 * 16 + l16];
        u3.f4 = h16[(size_t)s3 * 16 + l16];
#pragma unroll
        for (int p = 0; p < 4; p++) {
            float2 a = __half22float2(u0.h2[p]);
            float2 b = __half22float2(u1.h2[p]);
            float2 c = __half22float2(u2.h2[p]);
            float2 d = __half22float2(u3.h2[p]);
            acc[2 * p]     += (a.x + b.x) + (c.x + d.x);
            acc[2 * p + 1] += (a.y + b.y) + (c.y + d.y);
        }
    }
    for (; i < end; i += 4) {
        int s = col[i];
        HU u; u.f4 = h16[(size_t)s * 16 + l16];
#pragma unroll
        for (int p = 0; p < 4; p++) {
            float2 a = __half22float2(u.h2[p]);
            acc[2 * p]     += a.x;
            acc[2 * p + 1] += a.y;
        }
    }
#pragma unroll
    for (int mm = 16; mm <= 32; mm <<= 1)
#pragma unroll
        for (int j = 0; j < 8; j++) acc[j] += __shfl_xor(acc[j], mm);
    if (q == 0) {
        float s = inorm[w];
        bf16x8_t hv, lv;
#pragma unroll
        for (int j = 0; j < 8; j++) {
            float v = acc[j] * s;
            short hi = f2bf(v);
            hv[j] = hi;
            lv[j] = f2bf(v - bf2f(hi));
        }
        *(bf16x8_t*)&h0h[(size_t)w * 128 + l16 * 8] = hv;
        *(bf16x8_t*)&h0l[(size_t)w * 128 + l16 * 8] = lv;
    }
}

// ---------------------------------------------------------------- split-bf16 MFMA GEMM, operand-swapped epilogue (R5-proven)
// R9: TPB=512 for the 128-col GEMMs — 8 waves share the 64KB weight LDS, so
// the LDS cap (2 blocks/CU) now yields 16 waves/CU (50%) instead of 8 (25%).
// Waves stride tiles independently (no R4 group imbalance); grid 391 gives
// 3128 waves x 2 tiles = 6256 ~ 6250 (near-perfect balance).
template <int NT, int TPB, bool RELU, bool OUTSCALE, bool OUTHALF, bool INSPLIT>
__global__ __launch_bounds__(TPB) void mfma_gemm_k(
    const void* __restrict__ in, const short* __restrict__ inl,
    const float* __restrict__ W, const float* __restrict__ bias,
    void* __restrict__ outp, const float* __restrict__ outscale,
    int nrows, int ncols, int ntiles) {

    __shared__ short Bh[NT * 2048];   // [ntc][kblk(4)][lane(64)][j(8)]
    __shared__ short Bl[NT * 2048];

    const int t = threadIdx.x;

    if constexpr (NT == 8) {
        constexpr int NJ = (128 * 128) / (TPB * 4);
        for (int j = 0; j < NJ; j++) {
            int fi = (j * TPB + t) * 4;
            int k = fi >> 7, n0 = fi & 127;
            float4 wv = *(const float4*)(W + fi);
            float wa[4] = {wv.x, wv.y, wv.z, wv.w};
#pragma unroll
            for (int cc = 0; cc < 4; cc++) {
                int g = n0 + cc;
                int q2 = g >> 2;
                int ntc = q2 & 7;                       // % NT (NT=8)
                int c = ((q2 >> 3) << 2) | (g & 3);     // (q2/NT)*4 + (g&3)
                int kblk = k >> 5, ksub = k & 31;
                int lane_ = ((ksub >> 3) << 4) | c;
                int sidx = ((ntc * 4 + kblk) * 64 + lane_) * 8 + (ksub & 7);
                short hi = f2bf(wa[cc]);
                Bh[sidx] = hi; Bl[sidx] = f2bf(wa[cc] - bf2f(hi));
            }
        }
    } else {  // classifier: 40 real cols, pad to NT*16=48
        for (int idx = t; idx < 128 * 64; idx += TPB) {
            int k = idx >> 6, g = idx & 63;
            if (g < NT * 16) {
                float w = (g < 40) ? ((const float*)W)[k * 40 + g] : 0.f;
                int q2 = g >> 2;
                int ntc = q2 % NT;
                int c = (q2 / NT) * 4 + (g & 3);
                int kblk = k >> 5, ksub = k & 31;
                int lane_ = ((ksub >> 3) << 4) | c;
                int sidx = ((ntc * 4 + kblk) * 64 + lane_) * 8 + (ksub & 7);
                short hi = f2bf(w);
                Bh[sidx] = hi; Bl[sidx] = f2bf(w - bf2f(hi));
            }
        }
    }
    __syncthreads();   // LDS read-only below

    const int wave = t >> 6;
    const int lane = t & 63;
    const int m    = lane & 15;     // node within tile
    const int kq   = lane >> 4;
    const int cbase = kq * 4 * NT;  // this thread's first output col
    constexpr int WPB = TPB / 64;

    float bstat[4 * NT];
#pragma unroll
    for (int i = 0; i < 4 * NT; i++) {
        int g = cbase + i;
        bstat[i] = (g < ncols) ? bias[g] : 0.f;
    }

    const int wstride = gridDim.x * WPB;
    for (int tile = blockIdx.x * WPB + wave; tile < ntiles; tile += wstride) {
        int row = tile * 16 + m;
        bool rv = row < nrows;

        bf16x8_t Ah[4], Al[4];
        if constexpr (INSPLIT) {
            const short* ih = (const short*)in + (size_t)row * 128 + kq * 8;
            const short* il = inl + (size_t)row * 128 + kq * 8;
#pragma unroll
            for (int kb = 0; kb < 4; kb++) {
                if (rv) {
                    Ah[kb] = *(const bf16x8_t*)(ih + kb * 32);
                    Al[kb] = *(const bf16x8_t*)(il + kb * 32);
                } else {
                    Ah[kb] = (bf16x8_t){0,0,0,0,0,0,0,0};
                    Al[kb] = (bf16x8_t){0,0,0,0,0,0,0,0};
                }
            }
        } else {
#pragma unroll
            for (int kb = 0; kb < 4; kb++) {
                const float* ap = (const float*)in + (size_t)row * 128 + kb * 32 + kq * 8;
                float4 p0, p1;
                if (rv) { p0 = *(const float4*)ap; p1 = *(const float4*)(ap + 4); }
                else    { p0 = make_float4(0,0,0,0); p1 = make_float4(0,0,0,0); }
                float av[8] = {p0.x, p0.y, p0.z, p0.w, p1.x, p1.y, p1.z, p1.w};
#pragma unroll
                for (int j = 0; j < 8; j++) {
                    float v = av[j];
                    short hi = f2bf(v);
                    Ah[kb][j] = hi;
                    Al[kb][j] = f2bf(v - bf2f(hi));
                }
            }
        }

        float osc = 1.f;
        if (OUTSCALE && rv) osc = outscale[row];

        float ov[4 * NT] __attribute__((aligned(16)));
#pragma unroll
        for (int nt = 0; nt < NT; nt++) {
            f32x4_t acc = {0.f, 0.f, 0.f, 0.f};
#pragma unroll
            for (int kb = 0; kb < 4; kb++) {
                const bf16x8_t bh = *(const bf16x8_t*)&Bh[((nt * 4 + kb) * 64 + lane) * 8];
                const bf16x8_t bl = *(const bf16x8_t*)&Bl[((nt * 4 + kb) * 64 + lane) * 8];
                acc = __builtin_amdgcn_mfma_f32_16x16x32_bf16(bh, Ah[kb], acc, 0, 0, 0);
                acc = __builtin_amdgcn_mfma_f32_16x16x32_bf16(bh, Al[kb], acc, 0, 0, 0);
                acc = __builtin_amdgcn_mfma_f32_16x16x32_bf16(bl, Ah[kb], acc, 0, 0, 0);
            }
#pragma unroll
            for (int r = 0; r < 4; r++) {
                float v = acc[r] + bstat[nt * 4 + r];
                if (RELU) v = fmaxf(v, 0.f);
                ov[nt * 4 + r] = v * osc;
            }
        }

        if (rv) {
            if constexpr (OUTHALF) {
                union { __half h[4 * NT]; float4 f4[NT]; } U;
#pragma unroll
                for (int i = 0; i < 4 * NT; i++) U.h[i] = __float2half_rn(ov[i]);
                float4* p = (float4*)((__half*)outp + (size_t)row * ncols + cbase);
#pragma unroll
                for (int j = 0; j < NT; j += 2) p[j >> 1] = U.f4[j >> 1];   // NT=8: 4x16B
            } else if constexpr (NT == 8) {
                float4* p = (float4*)((float*)outp + (size_t)row * 128 + cbase);
#pragma unroll
                for (int j = 0; j < 8; j++) p[j] = ((const float4*)ov)[j];  // 8x16B
            } else {  // classifier fp32, ncols=40: cols cbase..cbase+11, skip >=40
                float* p = (float*)outp + (size_t)row * 40 + cbase;
#pragma unroll
                for (int j = 0; j < 3; j++) {
                    if (cbase + j * 4 < 40) *(float4*)(p + j * 4) = ((const float4*)ov)[j];
                }
            }
        }
    }
}

// ---------------------------------------------------------------- launch
extern "C" void kernel_launch(void* const* d_in, const int* in_sizes, int n_in,
                              void* d_out, int out_size, void* d_ws, size_t ws_size,
                              hipStream_t stream) {
    const float* x   = (const float*)d_in[0];
    const int*   src = (const int*)d_in[1];
    const int*   dst = (const int*)d_in[2];
    const float* W1  = (const float*)d_in[3];
    const float* b1  = (const float*)d_in[4];
    const float* W2  = (const float*)d_in[5];
    const float* b2  = (const float*)d_in[6];
    const float* Wg  = (const float*)d_in[7];   // [3][128][128]
    const float* bg  = (const float*)d_in[8];   // [3][128]
    const float* Wc  = (const float*)d_in[9];   // [128][40]
    const float* bc  = (const float*)d_in[10];  // [40]
    float* out = (float*)d_out;

    char* ws = (char*)d_ws;
    size_t off = 0;
    auto alloc = [&](size_t bytes) -> void* {
        void* p = ws + off;
        off += (bytes + 255) & ~(size_t)255;
        return p;
    };
    short*  h0h    = (short*)alloc((size_t)NN * HID * 2);    // agg out hi plane (bf16)
    short*  h0l    = (short*)alloc((size_t)NN * HID * 2);    // agg out lo plane (bf16)
    float*  h1     = (float*)alloc((size_t)NN * HID * 4);    // conv2 out (fp32)
    __half* h16    = (__half*)alloc((size_t)NN * HID * 2);   // agg in (fp16)
    float*  W12    = (float*)alloc(128 * 128 * 4);
    float*  b12    = (float*)alloc(128 * 4);
    float*  onorm  = (float*)alloc((size_t)NN * 4);
    float*  inorm  = (float*)alloc((size_t)NN * 4);
    int*    rowptr = (int*)alloc((size_t)(NN + 1) * 4);
    int*    col    = (int*)alloc((size_t)EE * 4);
    int*    bh2    = (int*)alloc((size_t)MH2 * 4);
    int*    off2   = (int*)alloc((size_t)MH2 * 4);
    int*    bsum   = (int*)alloc((size_t)NSC * 4);
    int*    boff   = (int*)alloc((size_t)NSC * 4);
    // sort payloads alias h0h/h0l (consumed by bucket_csr_ocnt_k before agg writes)
    unsigned*      pairs = (unsigned*)h0h;                          // 6.4 MB
    unsigned char* sbyte = (unsigned char*)h0h + (size_t)EE * 4;    // 1.6 MB (within h0h+h0l)

    // ---- CSR build (no global atomics): single merged scan over dst|src
    bh_both_k<<<NBE, 256, 0, stream>>>(src, dst, bh2);
    scan_sum_k<<<NSC, 256, 0, stream>>>(bh2, bsum, MH2);
    scan_top_k<<<1, 512, 0, stream>>>(bsum, boff, NSC);
    scan_chunk_k<<<NSC, 256, 0, stream>>>(bh2, boff, off2, MH2);
    scatter_both_k<<<NBE, 256, 0, stream>>>(src, dst, off2, pairs, sbyte);
    bucket_csr_ocnt_k<<<2 * NBUK, 512, 0, stream>>>(pairs, sbyte, off2,
                                                    rowptr, col, inorm, onorm);

    // ---- weight fusion (independent of CSR chain)
    w12_k<<<65, 256, 0, stream>>>(W1, W2, b1, b2, W12, b12);

    const int ntiles = NN / 16;          // 6250 (exact)
    const int ggrid  = 391;              // 3128 waves x 2 tiles = 6256 ~ ntiles

    // h16 = (x @ W12 + b12) * onorm           (fused feature1+feature2)
    mfma_gemm_k<8, 512, false, true, true, false><<<ggrid, 512, 0, stream>>>(
        x, nullptr, W12, b12, h16, onorm, NN, 128, ntiles);
    for (int l = 0; l < 3; l++) {
        // (h0h,h0l) = split( inorm * sum_{src} h16[src] )
        agg_k<<<(NN * 64 + 255) / 256, 256, 0, stream>>>(
            (const float4*)h16, rowptr, col, inorm, h0h, h0l);
        if (l < 2) {
            // h16 = relu(h0 @ Wg + bg) * onorm   (fp16 out, feeds agg)
            mfma_gemm_k<8, 512, true, true, true, true><<<ggrid, 512, 0, stream>>>(
                h0h, h0l, Wg + (size_t)l * 128 * 128, bg + (size_t)l * 128, h16, onorm, NN, 128, ntiles);
        } else {
            // h1 = relu(h0 @ Wg + bg)            (fp32, feeds classifier)
            mfma_gemm_k<8, 512, true, false, false, true><<<ggrid, 512, 0, stream>>>(
                h0h, h0l, Wg + (size_t)l * 128 * 128, bg + (size_t)l * 128, h1, nullptr, NN, 128, ntiles);
        }
    }
    // out = h1 @ Wc + bc  (classifier: 12KB LDS, already high occupancy)
    mfma_gemm_k<3, 256, false, false, false, false><<<512, 256, 0, stream>>>(
        h1, nullptr, Wc, bc, out, nullptr, NN, 40, ntiles);
}

// Round 10
// 552.908 us; speedup vs baseline: 1.5201x; 1.5201x over previous
//
#include <hip/hip_runtime.h>
#include <hip/hip_fp16.h>
#include <cstdint>
#include <cstddef>

constexpr int NN  = 100000;
constexpr int EE  = 1600000;
constexpr int HID = 128;
constexpr int BUK = 256;                      // nodes per bucket (local id fits 8 bits)
constexpr int NBUK = (NN + BUK - 1) / BUK;    // 391 buckets
constexpr int BLKE = 2048;                    // edges per block in bucket passes
constexpr int NBE  = (EE + BLKE - 1) / BLKE;  // 782 edge blocks
constexpr int MH   = NBUK * NBE;              // 305762 flattened hist entries
constexpr int MH2  = 2 * MH;                  // concatenated dst|src histograms
constexpr int NSC  = (MH2 + 2047) / 2048;     // 299 scan chunks (<=512 for scan_top)

typedef float f32x4_t __attribute__((ext_vector_type(4)));
typedef short bf16x8_t __attribute__((ext_vector_type(8)));

static __device__ __forceinline__ short f2bf(float f) {
    union { float f; unsigned u; } x; x.f = f;
    unsigned r = x.u + 0x7FFF + ((x.u >> 16) & 1);   // RN-even
    return (short)(r >> 16);
}
static __device__ __forceinline__ float bf2f(short b) {
    union { unsigned u; float f; } x; x.u = ((unsigned)(unsigned short)b) << 16;
    return x.f;
}

// ---------------------------------------------------------------- pass 1: per-block bucket histograms, both sides (LDS atomics only)
// dst half -> bh2[0..MH), src half -> bh2[MH..2MH)
__global__ __launch_bounds__(256) void bh_both_k(const int* __restrict__ src, const int* __restrict__ dst,
                                                 int* __restrict__ bh2) {
    __shared__ int hd[NBUK], hs[NBUK];
    int blk = blockIdx.x, t = threadIdx.x;
    for (int i = t; i < NBUK; i += 256) { hd[i] = 0; hs[i] = 0; }
    __syncthreads();
    int e0 = blk * BLKE, e1 = min(e0 + BLKE, EE);
    for (int e = e0 + t; e < e1; e += 256) {
        atomicAdd(&hd[dst[e] >> 8], 1);
        atomicAdd(&hs[src[e] >> 8], 1);
    }
    __syncthreads();
    for (int i = t; i < NBUK; i += 256) {
        bh2[i * NBE + blk]      = hd[i];
        bh2[MH + i * NBE + blk] = hs[i];
    }
}

// ---------------------------------------------------------------- 3-level exclusive scan over 2*MH (2048 elems/block)
__global__ __launch_bounds__(256) void scan_sum_k(const int* __restrict__ in, int* __restrict__ bsum, int n) {
    __shared__ int sc[256];
    int b = blockIdx.x, t = threadIdx.x;
    int base = b * 2048 + t * 8;
    int s = 0;
#pragma unroll
    for (int j = 0; j < 8; j++) { int idx = base + j; s += (idx < n) ? in[idx] : 0; }
    sc[t] = s; __syncthreads();
    for (int off = 128; off > 0; off >>= 1) {
        if (t < off) sc[t] += sc[t + off];
        __syncthreads();
    }
    if (t == 0) bsum[b] = sc[0];
}

__global__ __launch_bounds__(512) void scan_top_k(const int* __restrict__ bsum, int* __restrict__ boff, int nb) {
    __shared__ int sc[512];
    int t = threadIdx.x;
    int v = (t < nb) ? bsum[t] : 0;
    sc[t] = v; __syncthreads();
    for (int off = 1; off < 512; off <<= 1) {
        int u = (t >= off) ? sc[t - off] : 0;
        __syncthreads();
        sc[t] += u;
        __syncthreads();
    }
    if (t < nb) boff[t] = sc[t] - v;
}

__global__ __launch_bounds__(256) void scan_chunk_k(const int* __restrict__ in, const int* __restrict__ boff,
                                                    int* __restrict__ out, int n) {
    __shared__ int sc[256];
    int b = blockIdx.x, t = threadIdx.x;
    int base = b * 2048 + t * 8;
    int c[8];
    int s = 0;
#pragma unroll
    for (int j = 0; j < 8; j++) { int idx = base + j; c[j] = (idx < n) ? in[idx] : 0; s += c[j]; }
    sc[t] = s; __syncthreads();
    for (int off = 1; off < 256; off <<= 1) {
        int v = (t >= off) ? sc[t - off] : 0;
        __syncthreads();
        sc[t] += v;
        __syncthreads();
    }
    int excl = sc[t] - s + boff[b];
#pragma unroll
    for (int j = 0; j < 8; j++) {
        int idx = base + j;
        if (idx < n) out[idx] = excl;
        excl += c[j];
    }
}

// ---------------------------------------------------------------- pass 2: scatter into bucket order (LDS cursors)
// dst side: packed 25-bit payload (d_local<<17 | src); src side: low byte only
// src-half offsets carry +EE (concatenated scan) -> subtract at cursor load
__global__ __launch_bounds__(256) void scatter_both_k(const int* __restrict__ src, const int* __restrict__ dst,
                                                      const int* __restrict__ off2,
                                                      unsigned* __restrict__ pairs, unsigned char* __restrict__ sbyte) {
    __shared__ int cd[NBUK], cs[NBUK];
    int blk = blockIdx.x, t = threadIdx.x;
    for (int i = t; i < NBUK; i += 256) {
        cd[i] = off2[i * NBE + blk];
        cs[i] = off2[MH + i * NBE + blk] - EE;
    }
    __syncthreads();
    int e0 = blk * BLKE, e1 = min(e0 + BLKE, EE);
    for (int e = e0 + t; e < e1; e += 256) {
        int d = dst[e], s = src[e];
        int pd = atomicAdd(&cd[d >> 8], 1);
        pairs[pd] = ((unsigned)(d & 255) << 17) | (unsigned)s;
        int ps = atomicAdd(&cs[s >> 8], 1);
        sbyte[ps] = (unsigned char)(s & 255);
    }
}

// ---------------------------------------------------------------- per-bucket work, fused:
// blocks [0, NBUK):     in-deg hist -> inorm, rowptr, col  (from pairs)
// blocks [NBUK, 2*NBUK): out-deg hist -> onorm             (from sbyte)
__global__ __launch_bounds__(512) void bucket_csr_ocnt_k(
    const unsigned* __restrict__ pairs, const unsigned char* __restrict__ sbyte,
    const int* __restrict__ off2,
    int* __restrict__ rowptr, int* __restrict__ col,
    float* __restrict__ inorm, float* __restrict__ onorm) {
    __shared__ int hist[BUK];
    __shared__ int excl[BUK];
    __shared__ int psum[BUK];
    int t = threadIdx.x;

    if (blockIdx.x >= NBUK) {            // -------- out-degree counting
        int b = blockIdx.x - NBUK;
        int base = off2[MH + b * NBE] - EE;
        int endv = (b == NBUK - 1) ? EE : off2[MH + (b + 1) * NBE] - EE;
        if (t < BUK) hist[t] = 0;
        __syncthreads();
        for (int i = base + t; i < endv; i += 512) atomicAdd(&hist[sbyte[i]], 1);
        __syncthreads();
        if (t < BUK) {
            int node = b * BUK + t;
            if (node < NN) {
                int c = hist[t]; if (c < 1) c = 1;
                onorm[node] = rsqrtf((float)c);
            }
        }
        return;
    }

    // ------------------------------------------- CSR build
    int b = blockIdx.x;
    int base = off2[b * NBE];
    int endv = (b == NBUK - 1) ? EE : off2[(b + 1) * NBE];
    if (t < BUK) hist[t] = 0;
    __syncthreads();
    for (int i = base + t; i < endv; i += 512) atomicAdd(&hist[pairs[i] >> 17], 1);
    __syncthreads();
    int ps = 0;
    if (t < BUK) { ps = hist[t]; psum[t] = ps; }
    __syncthreads();
    for (int off = 1; off < BUK; off <<= 1) {
        int u = 0;
        if (t < BUK && t >= off) u = psum[t - off];
        __syncthreads();
        if (t < BUK) psum[t] += u;
        __syncthreads();
    }
    if (t < BUK) {
        int pex = psum[t] - ps;
        excl[t] = pex;
        int node = b * BUK + t;
        if (node < NN) {
            rowptr[node] = base + pex;
            int c = ps; if (c < 1) c = 1;
            inorm[node] = rsqrtf((float)c);
        }
    }
    if (b == NBUK - 1 && t == 0) rowptr[NN] = EE;
    __syncthreads();
    for (int i = base + t; i < endv; i += 512) {
        unsigned p = pairs[i];
        int pos = base + atomicAdd(&excl[p >> 17], 1);
        col[pos] = (int)(p & 0x1FFFFu);
    }
}

// ---------------------------------------------------------------- W12 = W1 @ W2 ; b12 = b1 @ W2 + b2 (merged)
__global__ __launch_bounds__(256) void w12_k(const float* __restrict__ W1, const float* __restrict__ W2,
                                             const float* __restrict__ b1, const float* __restrict__ b2,
                                             float* __restrict__ W12, float* __restrict__ b12) {
    if (blockIdx.x == 64) {
        int j = threadIdx.x;
        if (j < 128) {
            float acc = b2[j];
            for (int k = 0; k < 128; k++) acc = fmaf(b1[k], W2[k * 128 + j], acc);
            b12[j] = acc;
        }
        return;
    }
    int idx = blockIdx.x * 256 + threadIdx.x;   // 0..16383
    int i = idx >> 7, j = idx & 127;
    float a0 = 0.f, a1 = 0.f, a2 = 0.f, a3 = 0.f;
    for (int k = 0; k < 128; k += 4) {
        a0 = fmaf(W1[i * 128 + k],     W2[(k)     * 128 + j], a0);
        a1 = fmaf(W1[i * 128 + k + 1], W2[(k + 1) * 128 + j], a1);
        a2 = fmaf(W1[i * 128 + k + 2], W2[(k + 2) * 128 + j], a2);
        a3 = fmaf(W1[i * 128 + k + 3], W2[(k + 3) * 128 + j], a3);
    }
    W12[idx] = (a0 + a1) + (a2 + a3);
}

// ---------------------------------------------------------------- aggregation (fp16 gather, fp32 acc, split-bf16 out)
// R0-proven gather: one wave per dst node; quarter-wave (16 lanes x 16B =
// one 256B fp16 row), 4 edges in flight per quarter, 1-edge tail. h16 is
// pre-scaled by onorm. R8: epilogue scales by inorm and emits SPLIT-BF16
// planes (hi, lo) directly (bit-identical to the GEMM's old conversion).
__global__ __launch_bounds__(256) void agg_k(const float4* __restrict__ h16, const int* __restrict__ rowptr,
                                             const int* __restrict__ col, const float* __restrict__ inorm,
                                             short* __restrict__ h0h, short* __restrict__ h0l) {
    int w = (int)((blockIdx.x * 256 + threadIdx.x) >> 6);
    if (w >= NN) return;
    int lane = threadIdx.x & 63;
    int q   = lane >> 4;
    int l16 = lane & 15;
    int beg = rowptr[w], end = rowptr[w + 1];
    float acc[8];
#pragma unroll
    for (int j = 0; j < 8; j++) acc[j] = 0.f;

    union HU { float4 f4; __half2 h2[4]; };
    int i = beg + q;
    for (; i + 12 < end; i += 16) {        // per quarter: edges i, i+4, i+8, i+12
        int s0 = col[i], s1 = col[i + 4], s2 = col[i + 8], s3 = col[i + 12];
        HU u0, u1, u2, u3;
        u0.f4 = h16[(size_t)s0 * 16 + l16];
        u1.f4 = h16[(size_t)s1 * 16 + l16];
        u2.f4 = h16[(size_t)s2 * 16 + l16];
        u3.f4 = h16[(size_t)s3 * 16 + l16];
#pragma unroll
        for (int p = 0; p < 4; p++) {
            float2 a = __half22float2(u0.h2[p]);
            float2 b = __half22float2(u1.h2[p]);
            float2 c = __half22float2(u2.h2[p]);
            float2 d = __half22float2(u3.h2[p]);
            acc[2 * p]     += (a.x + b.x) + (c.x + d.x);
            acc[2 * p + 1] += (a.y + b.y) + (c.y + d.y);
        }
    }
    for (; i < end; i += 4) {
        int s = col[i];
        HU u; u.f4 = h16[(size_t)s * 16 + l16];
#pragma unroll
        for (int p = 0; p < 4; p++) {
            float2 a = __half22float2(u.h2[p]);
            acc[2 * p]     += a.x;
            acc[2 * p + 1] += a.y;
        }
    }
#pragma unroll
    for (int mm = 16; mm <= 32; mm <<= 1)
#pragma unroll
        for (int j = 0; j < 8; j++) acc[j] += __shfl_xor(acc[j], mm);
    if (q == 0) {
        float s = inorm[w];
        bf16x8_t hv, lv;
#pragma unroll
        for (int j = 0; j < 8; j++) {
            float v = acc[j] * s;
            short hi = f2bf(v);
            hv[j] = hi;
            lv[j] = f2bf(v - bf2f(hi));
        }
        *(bf16x8_t*)&h0h[(size_t)w * 128 + l16 * 8] = hv;
        *(bf16x8_t*)&h0l[(size_t)w * 128 + l16 * 8] = lv;
    }
}

// ---------------------------------------------------------------- split-bf16 MFMA GEMM, operand-swapped epilogue (R5-proven)
// R8: INSPLIT loads pre-split planes. R10: OUTHALF store goes through a
// per-wave 16x128 fp16 LDS tile (XOR-swizzled) so each wave-store
// instruction writes a CONTIGUOUS 1KB run — R9 counters proved the direct
// path writes one 16B piece per 64B sector per instruction -> partial-sector
// RMW (WRITE 25.6->118MB, FETCH +60MB). Wave-local LDS: no barrier needed
// (lgkmcnt orders same-wave ds ops). Requires nrows % 16 == 0 (NN is).
template <int NT, bool RELU, bool OUTSCALE, bool OUTHALF, bool INSPLIT>
__global__ __launch_bounds__(256) void mfma_gemm_k(
    const void* __restrict__ in, const short* __restrict__ inl,
    const float* __restrict__ W, const float* __restrict__ bias,
    void* __restrict__ outp, const float* __restrict__ outscale,
    int nrows, int ncols, int ntiles) {

    __shared__ short Bh[NT * 2048];   // [ntc][kblk(4)][lane(64)][j(8)]
    __shared__ short Bl[NT * 2048];
    __shared__ __half Tr[OUTHALF ? 4 * 16 * 128 : 1];   // per-wave 16x128 transpose tile (16KB)

    const int t = threadIdx.x;

    if constexpr (NT == 8) {
        for (int j = 0; j < 16; j++) {
            int fi = (j * 256 + t) * 4;
            int k = fi >> 7, n0 = fi & 127;
            float4 wv = *(const float4*)(W + fi);
            float wa[4] = {wv.x, wv.y, wv.z, wv.w};
#pragma unroll
            for (int cc = 0; cc < 4; cc++) {
                int g = n0 + cc;
                int q2 = g >> 2;
                int ntc = q2 & 7;                       // % NT (NT=8)
                int c = ((q2 >> 3) << 2) | (g & 3);     // (q2/NT)*4 + (g&3)
                int kblk = k >> 5, ksub = k & 31;
                int lane_ = ((ksub >> 3) << 4) | c;
                int sidx = ((ntc * 4 + kblk) * 64 + lane_) * 8 + (ksub & 7);
                short hi = f2bf(wa[cc]);
                Bh[sidx] = hi; Bl[sidx] = f2bf(wa[cc] - bf2f(hi));
            }
        }
    } else {  // classifier: 40 real cols, pad to NT*16=48
        for (int idx = t; idx < 128 * 64; idx += 256) {
            int k = idx >> 6, g = idx & 63;
            if (g < NT * 16) {
                float w = (g < 40) ? ((const float*)W)[k * 40 + g] : 0.f;
                int q2 = g >> 2;
                int ntc = q2 % NT;
                int c = (q2 / NT) * 4 + (g & 3);
                int kblk = k >> 5, ksub = k & 31;
                int lane_ = ((ksub >> 3) << 4) | c;
                int sidx = ((ntc * 4 + kblk) * 64 + lane_) * 8 + (ksub & 7);
                short hi = f2bf(w);
                Bh[sidx] = hi; Bl[sidx] = f2bf(w - bf2f(hi));
            }
        }
    }
    __syncthreads();   // Bh/Bl read-only below

    const int wave = t >> 6;
    const int lane = t & 63;
    const int m    = lane & 15;     // node within tile
    const int kq   = lane >> 4;
    const int cbase = kq * 4 * NT;  // this thread's first output col

    float bstat[4 * NT];
#pragma unroll
    for (int i = 0; i < 4 * NT; i++) {
        int g = cbase + i;
        bstat[i] = (g < ncols) ? bias[g] : 0.f;
    }

    const int wstride = gridDim.x * 4;
    for (int tile = blockIdx.x * 4 + wave; tile < ntiles; tile += wstride) {
        int row = tile * 16 + m;
        bool rv = row < nrows;

        bf16x8_t Ah[4], Al[4];
        if constexpr (INSPLIT) {
            const short* ih = (const short*)in + (size_t)row * 128 + kq * 8;
            const short* il = inl + (size_t)row * 128 + kq * 8;
#pragma unroll
            for (int kb = 0; kb < 4; kb++) {
                if (rv) {
                    Ah[kb] = *(const bf16x8_t*)(ih + kb * 32);
                    Al[kb] = *(const bf16x8_t*)(il + kb * 32);
                } else {
                    Ah[kb] = (bf16x8_t){0,0,0,0,0,0,0,0};
                    Al[kb] = (bf16x8_t){0,0,0,0,0,0,0,0};
                }
            }
        } else {
#pragma unroll
            for (int kb = 0; kb < 4; kb++) {
                const float* ap = (const float*)in + (size_t)row * 128 + kb * 32 + kq * 8;
                float4 p0, p1;
                if (rv) { p0 = *(const float4*)ap; p1 = *(const float4*)(ap + 4); }
                else    { p0 = make_float4(0,0,0,0); p1 = make_float4(0,0,0,0); }
                float av[8] = {p0.x, p0.y, p0.z, p0.w, p1.x, p1.y, p1.z, p1.w};
#pragma unroll
                for (int j = 0; j < 8; j++) {
                    float v = av[j];
                    short hi = f2bf(v);
                    Ah[kb][j] = hi;
                    Al[kb][j] = f2bf(v - bf2f(hi));
                }
            }
        }

        float osc = 1.f;
        if (OUTSCALE && rv) osc = outscale[row];

        float ov[4 * NT] __attribute__((aligned(16)));
#pragma unroll
        for (int nt = 0; nt < NT; nt++) {
            f32x4_t acc = {0.f, 0.f, 0.f, 0.f};
#pragma unroll
            for (int kb = 0; kb < 4; kb++) {
                const bf16x8_t bh = *(const bf16x8_t*)&Bh[((nt * 4 + kb) * 64 + lane) * 8];
                const bf16x8_t bl = *(const bf16x8_t*)&Bl[((nt * 4 + kb) * 64 + lane) * 8];
                acc = __builtin_amdgcn_mfma_f32_16x16x32_bf16(bh, Ah[kb], acc, 0, 0, 0);
                acc = __builtin_amdgcn_mfma_f32_16x16x32_bf16(bh, Al[kb], acc, 0, 0, 0);
                acc = __builtin_amdgcn_mfma_f32_16x16x32_bf16(bl, Ah[kb], acc, 0, 0, 0);
            }
#pragma unroll
            for (int r = 0; r < 4; r++) {
                float v = acc[r] + bstat[nt * 4 + r];
                if (RELU) v = fmaxf(v, 0.f);
                ov[nt * 4 + r] = v * osc;
            }
        }

        if constexpr (OUTHALF) {
            // coalesced store via per-wave LDS transpose (nrows % 16 == 0)
            __half* tw = &Tr[wave * 2048];
#pragma unroll
            for (int p = 0; p < 4; p++) {
                union { __half h[8]; float4 f4; } U;
#pragma unroll
                for (int j = 0; j < 8; j++) U.h[j] = __float2half_rn(ov[p * 8 + j]);
                int bo = (cbase * 2 + p * 16) ^ ((m & 7) << 4);   // XOR-swizzle within row
                *(float4*)((char*)(tw + m * 128) + bo) = U.f4;
            }
            // read back: instruction s covers 4 rows x 256B = contiguous 1KB global
#pragma unroll
            for (int s2 = 0; s2 < 4; s2++) {
                int r = s2 * 4 + (lane >> 4);
                int bo = ((lane & 15) * 16) ^ ((r & 7) << 4);
                float4 v = *(const float4*)((char*)(tw + r * 128) + bo);
                *(float4*)((__half*)outp + (size_t)(tile * 16 + r) * ncols + (lane & 15) * 8) = v;
            }
        } else if (rv) {
            if constexpr (NT == 8) {
                float4* p = (float4*)((float*)outp + (size_t)row * 128 + cbase);
#pragma unroll
                for (int j = 0; j < 8; j++) p[j] = ((const float4*)ov)[j];  // 128B contiguous/thread
            } else {  // classifier fp32, ncols=40: cols cbase..cbase+11, skip >=40
                float* p = (float*)outp + (size_t)row * 40 + cbase;
#pragma unroll
                for (int j = 0; j < 3; j++) {
                    if (cbase + j * 4 < 40) *(float4*)(p + j * 4) = ((const float4*)ov)[j];
                }
            }
        }
    }
}

// ---------------------------------------------------------------- launch
extern "C" void kernel_launch(void* const* d_in, const int* in_sizes, int n_in,
                              void* d_out, int out_size, void* d_ws, size_t ws_size,
                              hipStream_t stream) {
    const float* x   = (const float*)d_in[0];
    const int*   src = (const int*)d_in[1];
    const int*   dst = (const int*)d_in[2];
    const float* W1  = (const float*)d_in[3];
    const float* b1  = (const float*)d_in[4];
    const float* W2  = (const float*)d_in[5];
    const float* b2  = (const float*)d_in[6];
    const float* Wg  = (const float*)d_in[7];   // [3][128][128]
    const float* bg  = (const float*)d_in[8];   // [3][128]
    const float* Wc  = (const float*)d_in[9];   // [128][40]
    const float* bc  = (const float*)d_in[10];  // [40]
    float* out = (float*)d_out;

    char* ws = (char*)d_ws;
    size_t off = 0;
    auto alloc = [&](size_t bytes) -> void* {
        void* p = ws + off;
        off += (bytes + 255) & ~(size_t)255;
        return p;
    };
    short*  h0h    = (short*)alloc((size_t)NN * HID * 2);    // agg out hi plane (bf16)
    short*  h0l    = (short*)alloc((size_t)NN * HID * 2);    // agg out lo plane (bf16)
    float*  h1     = (float*)alloc((size_t)NN * HID * 4);    // conv2 out (fp32)
    __half* h16    = (__half*)alloc((size_t)NN * HID * 2);   // agg in (fp16)
    float*  W12    = (float*)alloc(128 * 128 * 4);
    float*  b12    = (float*)alloc(128 * 4);
    float*  onorm  = (float*)alloc((size_t)NN * 4);
    float*  inorm  = (float*)alloc((size_t)NN * 4);
    int*    rowptr = (int*)alloc((size_t)(NN + 1) * 4);
    int*    col    = (int*)alloc((size_t)EE * 4);
    int*    bh2    = (int*)alloc((size_t)MH2 * 4);
    int*    off2   = (int*)alloc((size_t)MH2 * 4);
    int*    bsum   = (int*)alloc((size_t)NSC * 4);
    int*    boff   = (int*)alloc((size_t)NSC * 4);
    // sort payloads alias h0h/h0l (consumed by bucket_csr_ocnt_k before agg writes)
    unsigned*      pairs = (unsigned*)h0h;                          // 6.4 MB
    unsigned char* sbyte = (unsigned char*)h0h + (size_t)EE * 4;    // 1.6 MB (within h0h+h0l)

    // ---- CSR build (no global atomics): single merged scan over dst|src
    bh_both_k<<<NBE, 256, 0, stream>>>(src, dst, bh2);
    scan_sum_k<<<NSC, 256, 0, stream>>>(bh2, bsum, MH2);
    scan_top_k<<<1, 512, 0, stream>>>(bsum, boff, NSC);
    scan_chunk_k<<<NSC, 256, 0, stream>>>(bh2, boff, off2, MH2);
    scatter_both_k<<<NBE, 256, 0, stream>>>(src, dst, off2, pairs, sbyte);
    bucket_csr_ocnt_k<<<2 * NBUK, 512, 0, stream>>>(pairs, sbyte, off2,
                                                    rowptr, col, inorm, onorm);

    // ---- weight fusion (independent of CSR chain)
    w12_k<<<65, 256, 0, stream>>>(W1, W2, b1, b2, W12, b12);

    const int ntiles = NN / 16;          // 6250 (exact)
    const int ggrid  = 512;              // 2 blocks/CU (80KB LDS)

    // h16 = (x @ W12 + b12) * onorm           (fused feature1+feature2)
    mfma_gemm_k<8, false, true, true, false><<<ggrid, 256, 0, stream>>>(
        x, nullptr, W12, b12, h16, onorm, NN, 128, ntiles);
    for (int l = 0; l < 3; l++) {
        // (h0h,h0l) = split( inorm * sum_{src} h16[src] )
        agg_k<<<(NN * 64 + 255) / 256, 256, 0, stream>>>(
            (const float4*)h16, rowptr, col, inorm, h0h, h0l);
        if (l < 2) {
            // h16 = relu(h0 @ Wg + bg) * onorm   (fp16 out, feeds agg)
            mfma_gemm_k<8, true, true, true, true><<<ggrid, 256, 0, stream>>>(
                h0h, h0l, Wg + (size_t)l * 128 * 128, bg + (size_t)l * 128, h16, onorm, NN, 128, ntiles);
        } else {
            // h1 = relu(h0 @ Wg + bg)            (fp32, feeds classifier)
            mfma_gemm_k<8, true, false, false, true><<<ggrid, 256, 0, stream>>>(
                h0h, h0l, Wg + (size_t)l * 128 * 128, bg + (size_t)l * 128, h1, nullptr, NN, 128, ntiles);
        }
    }
    // out = h1 @ Wc + bc
    mfma_gemm_k<3, false, false, false, false><<<ggrid, 256, 0, stream>>>(
        h1, nullptr, Wc, bc, out, nullptr, NN, 40, ntiles);
}